// Round 5
// baseline (504.158 us; speedup 1.0000x reference)
//
#include <hip/hip_runtime.h>
#include <math.h>

// Fused morphological opening: erode(10x10 flat, SAME) then dilate(10x10 flat,
// SAME), NHWC fp32 [16,512,512,8]. One kernel; eroded intermediate in LDS.
//
// R4 post-mortem: GW-16 runs + interior fast paths -> 103 us (conflicts 5.2M).
// All pipes ~1/3 (VALU 36, LDS ~35, HBM 29), occupancy 38% capped at 50% by
// 64.9 KB LDS -> latency/duty-cycle bound on the serial phase chain.
// R5: retest occupancy WITH the efficient structure (R3's failure used the
// old run-8 code, +22% work): TH=23/RA=32 -> LDS 32*101*16 = 51,712 B ->
// 3 blocks/CU (75% cap). Geometry now exact: P1 runs {16,16}, P3 {16,7}
// (no scratch rows), P2 remapped to 100% fill over 3 waves.
// launch_bounds(512,6) pins VGPR <= 85 so 3 blocks/CU survive regalloc.
//
// Phases (single LDS buffer, in-place via read-stage -> barrier -> write):
//   P1 minV : global -> sA   32 rows (h0-4..h0+27) x 100 f4, runs {16,16}
//   P2 minH : sA -> sA       32 rows x 41 px,  runs {14,14,13} (taps fit 50px)
//   P3 maxV : sA -> sA       23 rows x 82 f4,  runs {16,7}
//   P4 maxH : sA -> sA       23 rows x 32 px,  runs {16,16}
//   P5 copy : sA -> global   coalesced 1KB/wave
// Gil-Werman run: R outputs from R+9 taps (window 10), two chained chunks.
// Boundary semantics (lax.reduce_window SAME): erosion pads input +inf (P1
// stages pinf for OOB); dilation pads the *eroded* image -inf outside [0,512)
// (masks only on rim blocks: by in {0,21,22} or bx in {0,15}).

#define W_F4   1024              // 512 px * 2 f4 (8 ch)
#define IMG_F4 (512 * W_F4)
#define TH     23                // output rows per tile
#define TW     32                // output px per tile
#define RA     32                // sA rows = TH + 9
#define CA     100               // minV cols (f4) = (TW + 18) * 2
#define S_A    101               // sA row stride (f4)
#define NJ     41                // eroded px per row = TW + 9

__device__ __forceinline__ float4 f4min(float4 a, float4 b) {
    return make_float4(fminf(a.x,b.x), fminf(a.y,b.y), fminf(a.z,b.z), fminf(a.w,b.w));
}
__device__ __forceinline__ float4 f4max(float4 a, float4 b) {
    return make_float4(fmaxf(a.x,b.x), fmaxf(a.y,b.y), fmaxf(a.z,b.z), fmaxf(a.w,b.w));
}
template<bool MIN>
__device__ __forceinline__ float4 f4op(float4 a, float4 b) {
    return MIN ? f4min(a, b) : f4max(a, b);
}

// Gil-Werman run: o[i] = reduce(tap(i)..tap(i+9)) for i in [0,R), 1<=R<=16.
// Reads taps q in [0, R+9) only (chunk1 suffix capped at C1 = min(R,8)).
template<int R, bool MIN, class F>
__device__ __forceinline__ void gw_run(F tap, float4* o) {
    constexpr int C1 = (R < 8) ? R : 8;
    float4 v8, L[9];
    {
        float4 v[9];
#pragma unroll
        for (int q = 0; q < 9; q++) v[q] = tap(q);
        v8 = v[8];
        L[8] = v[8];
#pragma unroll
        for (int i = 7; i >= 0; i--) L[i] = f4op<MIN>(v[i], L[i + 1]);
    }
    float4 w[8], rr;
#pragma unroll
    for (int i = 0; i < C1; i++) {           // taps 9..8+C1
        float4 tv = tap(9 + i);
        w[i] = tv;
        rr = i ? f4op<MIN>(rr, tv) : tv;
        o[i] = f4op<MIN>(L[i], rr);
    }
    if (R > 8) {
        float4 L2[9];
        L2[8] = w[7];                        // tap 16
#pragma unroll
        for (int i = 7; i >= 1; i--) L2[i] = f4op<MIN>(w[i - 1], L2[i + 1]);
        L2[0] = f4op<MIN>(v8, L2[1]);
        float4 r2;
#pragma unroll
        for (int i = 0; i < R - 8; i++) {    // taps 17..R+8
            float4 tv = tap(17 + i);
            r2 = i ? f4op<MIN>(r2, tv) : tv;
            o[8 + i] = f4op<MIN>(L2[i], r2);
        }
    }
}

__global__ __launch_bounds__(512, 6) void opening(const float4* __restrict__ in,
                                                  float4* __restrict__ out) {
    __shared__ float4 sA[RA * S_A];          // 51,712 B -> 3 blocks/CU

    const float4 pinf4 = make_float4( INFINITY,  INFINITY,  INFINITY,  INFINITY);
    const float4 ninf4 = make_float4(-INFINITY, -INFINITY, -INFINITY, -INFINITY);

    const int t  = threadIdx.x;
    const int h0 = blockIdx.y * TH;          // last band ragged (h0 = 506)
    const int w0 = blockIdx.x * TW;
    const bool yin = (h0 >= 8) && (h0 + RA < 512);        // P1 taps h0-8..h0+32
    const bool xin = (w0 >= 8) && (2 * w0 + 83 < W_F4);   // bx in [1,14]

    const float4* img  = in  + (size_t)blockIdx.z * IMG_F4;
    float4*       oimg = out + (size_t)blockIdx.z * IMG_F4;

    // ---- P1: vertical min, global -> sA. (c in [0,100)) x runs {16,16} ----
    // sA row s <-> eroded abs row h0-4+s; taps for s: input rows h0-8+s..h0+1+s.
    if (t < 2 * 128) {
        const int p  = t >> 7;               // wave-uniform run id (2 waves/run)
        const int id = t & 127;
        if (id < CA) {
            const int s0    = p * 16;
            const int hbase = h0 - 8 + s0;
            const int colf4 = w0 * 2 - 16 + id;
            float4 o[16];
            if (yin) {
                const bool colok = (colf4 >= 0) & (colf4 < W_F4);  // xin -> true
                if (colok) {
                    auto tap = [&](int q) { return img[(size_t)(hbase + q) * W_F4 + colf4]; };
                    gw_run<16, true>(tap, o);
#pragma unroll
                    for (int i = 0; i < 16; i++) sA[(s0 + i) * S_A + id] = o[i];
                } else {                     // whole column OOB -> +inf
#pragma unroll
                    for (int i = 0; i < 16; i++) sA[(s0 + i) * S_A + id] = pinf4;
                }
            } else {                         // rim: per-tap mask
                auto tap = [&](int q) {
                    int h = hbase + q;
                    bool ok = (colf4 >= 0) & (colf4 < W_F4) & (h >= 0) & (h < 512);
                    return ok ? img[(size_t)h * W_F4 + colf4] : pinf4;
                };
                gw_run<16, true>(tap, o);
#pragma unroll
                for (int i = 0; i < 16; i++) sA[(s0 + i) * S_A + id] = o[i];
            }
        }
    }
    __syncthreads();

    // ---- P2: horizontal min, sA -> sA in place. 192 tasks, 3 waves 100% fill ----
    // task t<192: c4 = t&1, row = (t>>1)&31, run u = t>>6 (wave-uniform).
    // out j in [j0, j0+R): eroded px w0-4+j; taps minV px j..j+9 (staged 50 px).
    // No masks: P1 staged +inf for OOB. Max tap col: u=2,q=21 -> 2*49+1 = 99.
    {
        const bool act = t < 192;
        const int u  = t >> 6;               // 0,1,2 wave-uniform
        int base = 0, j0 = 0;
        float4 o[14];
        if (act) {
            base = ((t >> 1) & 31) * S_A + (t & 1);
            j0 = u * 14;                     // 0,14,28
            auto tap = [&](int q) { return sA[base + 2 * (j0 + q)]; };
            if (u < 2) gw_run<14, true>(tap, o);
            else       gw_run<13, true>(tap, o);
        }
        __syncthreads();                     // all reads done before any write
        if (act) {
            if (u < 2) {
#pragma unroll
                for (int i = 0; i < 14; i++) sA[base + 2 * (j0 + i)] = o[i];
            } else {
#pragma unroll
                for (int i = 0; i < 13; i++) sA[base + 2 * (j0 + i)] = o[i];
            }
        }
    }
    __syncthreads();

    // ---- P3: vertical max, sA -> sA rows [0,23). (c in [0,82)) x runs {16,7} ----
    // out o: abs row h0+o; taps eroded rows s=o..o+9 (s<=31, exact). Tap = -inf
    // when eroded abs row h0-4+s outside [0,512) (dilation pads eroded -inf).
    {
        const int u  = t >> 7;               // wave-uniform (2 waves/run)
        const int id = t & 127;
        const bool act = (t < 2 * 128) && (id < 82);
        int c = 0, o0 = 0;
        float4 o[16];
        if (act) {
            c  = id;
            o0 = u * 16;                     // 0,16
            if (yin) {
                auto tap = [&](int q) { return sA[(o0 + q) * S_A + c]; };
                if (u == 0) gw_run<16, false>(tap, o);
                else        gw_run< 7, false>(tap, o);
            } else {
                auto tap = [&](int q) {
                    int s = o0 + q;
                    float4 val = sA[s * S_A + c];
                    int h = h0 - 4 + s;
                    return ((h >= 0) & (h < 512)) ? val : ninf4;
                };
                if (u == 0) gw_run<16, false>(tap, o);
                else        gw_run< 7, false>(tap, o);
            }
        }
        __syncthreads();                     // all reads done before any write
        if (act) {
            const int Rn = (u == 0) ? 16 : 7;
#pragma unroll
            for (int i = 0; i < 16; i++)
                if (i < Rn) sA[(o0 + i) * S_A + c] = o[i];
        }
    }
    __syncthreads();

    // ---- P4: horizontal max, sA -> sA cols [0,64). (c4 x 23 rows) x runs {16,16} ----
    // out x: px w0+x; taps eroded j=x..x+9 (j <= 40, exact). Tap = -inf when
    // eroded abs px w0-4+j outside [0,512).
    {
        const int u  = t >> 6;               // wave-uniform
        const int id = t & 63;
        const bool act = (t < 2 * 64) && (id < 2 * TH);
        int base = 0, x0 = 0;
        float4 o[16];
        if (act) {
            base = (id >> 1) * S_A + (id & 1);
            x0 = u * 16;                     // 0,16
            if (xin) {
                auto tap = [&](int q) { return sA[base + 2 * (x0 + q)]; };
                gw_run<16, false>(tap, o);
            } else {
                auto tap = [&](int q) {
                    int j = x0 + q;
                    float4 val = sA[base + 2 * j];
                    int px = w0 - 4 + j;
                    return ((px >= 0) & (px < 512)) ? val : ninf4;
                };
                gw_run<16, false>(tap, o);
            }
        }
        __syncthreads();                     // all reads done before any write
        if (act) {
#pragma unroll
            for (int i = 0; i < 16; i++)     // cols <= 63
                sA[base + 2 * (x0 + i)] = o[i];
        }
    }
    __syncthreads();

    // ---- P5: coalesced copy sA -> global (lanes = consecutive f4, 1 KB/wave) ----
    for (int idx = t; idx < TH * 64; idx += 512) {
        int r = idx >> 6;
        int c = idx & 63;
        int h = h0 + r;
        if (h < 512)
            oimg[(size_t)h * W_F4 + (size_t)(w0 * 2 + c)] = sA[r * S_A + c];
    }
}

extern "C" void kernel_launch(void* const* d_in, const int* in_sizes, int n_in,
                              void* d_out, int out_size, void* d_ws, size_t ws_size,
                              hipStream_t stream) {
    const float4* in  = (const float4*)d_in[0];
    float4*       out = (float4*)d_out;
    (void)d_ws; (void)ws_size;               // workspace not needed

    dim3 grid(512 / TW, (512 + TH - 1) / TH, 16);   // 16 x 23 x 16 = 5888 blocks
    opening<<<grid, 512, 0, stream>>>(in, out);
}

// Round 6
// 273.136 us; speedup vs baseline: 1.8458x; 1.8458x over previous
//
#include <hip/hip_runtime.h>
#include <math.h>

// Fused morphological opening: erode(10x10 flat, SAME) then dilate(10x10 flat,
// SAME), NHWC fp32 [16,512,512,8]. One kernel; eroded intermediate in LDS.
//
// R5 post-mortem: launch_bounds(512,6) -> VGPR capped at 40 -> gw_run's o[16]
// (64 VGPRs live) SPILLED to scratch: WRITE_SIZE 131->600 MB, FETCH 104->264
// MB, VALUBusy 11%, 350 us. The 3-blocks/CU hypothesis was never tested.
// R6: SAME geometry (TH=23, RA=32, LDS 51,712 B -> 3 blocks/CU by LDS), but
// launch_bounds(512,4) so the allocator has room (~64 VGPR like R4, no spill).
// VGPR=64 allows 8 waves/SIMD, so LDS is the only occupancy cap: 75%.
//
// Phases (single LDS buffer, in-place via read-stage -> barrier -> write):
//   P1 minV : global -> sA   32 rows (h0-4..h0+27) x 100 f4, runs {16,16}
//   P2 minH : sA -> sA       32 rows x 41 px,  runs {14,14,13} (taps fit 50px)
//   P3 maxV : sA -> sA       23 rows x 82 f4,  runs {16,7}
//   P4 maxH : sA -> sA       23 rows x 32 px,  runs {16,16}
//   P5 copy : sA -> global   coalesced 1KB/wave
// Gil-Werman run: R outputs from R+9 taps (window 10), two chained chunks.
// Boundary semantics (lax.reduce_window SAME): erosion pads input +inf (P1
// stages pinf for OOB); dilation pads the *eroded* image -inf outside [0,512)
// (masks only on rim blocks).
// Decision rule going in: if occupancy >=55% and dur >=100 us, occupancy lever
// is dead -> R7 restructures the phase chain.

#define W_F4   1024              // 512 px * 2 f4 (8 ch)
#define IMG_F4 (512 * W_F4)
#define TH     23                // output rows per tile
#define TW     32                // output px per tile
#define RA     32                // sA rows = TH + 9
#define CA     100               // minV cols (f4) = (TW + 18) * 2
#define S_A    101               // sA row stride (f4)
#define NJ     41                // eroded px per row = TW + 9

__device__ __forceinline__ float4 f4min(float4 a, float4 b) {
    return make_float4(fminf(a.x,b.x), fminf(a.y,b.y), fminf(a.z,b.z), fminf(a.w,b.w));
}
__device__ __forceinline__ float4 f4max(float4 a, float4 b) {
    return make_float4(fmaxf(a.x,b.x), fmaxf(a.y,b.y), fmaxf(a.z,b.z), fmaxf(a.w,b.w));
}
template<bool MIN>
__device__ __forceinline__ float4 f4op(float4 a, float4 b) {
    return MIN ? f4min(a, b) : f4max(a, b);
}

// Gil-Werman run: o[i] = reduce(tap(i)..tap(i+9)) for i in [0,R), 1<=R<=16.
// Reads taps q in [0, R+9) only (chunk1 suffix capped at C1 = min(R,8)).
template<int R, bool MIN, class F>
__device__ __forceinline__ void gw_run(F tap, float4* o) {
    constexpr int C1 = (R < 8) ? R : 8;
    float4 v8, L[9];
    {
        float4 v[9];
#pragma unroll
        for (int q = 0; q < 9; q++) v[q] = tap(q);
        v8 = v[8];
        L[8] = v[8];
#pragma unroll
        for (int i = 7; i >= 0; i--) L[i] = f4op<MIN>(v[i], L[i + 1]);
    }
    float4 w[8], rr;
#pragma unroll
    for (int i = 0; i < C1; i++) {           // taps 9..8+C1
        float4 tv = tap(9 + i);
        w[i] = tv;
        rr = i ? f4op<MIN>(rr, tv) : tv;
        o[i] = f4op<MIN>(L[i], rr);
    }
    if (R > 8) {
        float4 L2[9];
        L2[8] = w[7];                        // tap 16
#pragma unroll
        for (int i = 7; i >= 1; i--) L2[i] = f4op<MIN>(w[i - 1], L2[i + 1]);
        L2[0] = f4op<MIN>(v8, L2[1]);
        float4 r2;
#pragma unroll
        for (int i = 0; i < R - 8; i++) {    // taps 17..R+8
            float4 tv = tap(17 + i);
            r2 = i ? f4op<MIN>(r2, tv) : tv;
            o[8 + i] = f4op<MIN>(L2[i], r2);
        }
    }
}

__global__ __launch_bounds__(512, 4) void opening(const float4* __restrict__ in,
                                                  float4* __restrict__ out) {
    __shared__ float4 sA[RA * S_A];          // 51,712 B -> 3 blocks/CU (LDS cap)

    const float4 pinf4 = make_float4( INFINITY,  INFINITY,  INFINITY,  INFINITY);
    const float4 ninf4 = make_float4(-INFINITY, -INFINITY, -INFINITY, -INFINITY);

    const int t  = threadIdx.x;
    const int h0 = blockIdx.y * TH;          // last band ragged (h0 = 506)
    const int w0 = blockIdx.x * TW;
    const bool yin = (h0 >= 8) && (h0 + RA < 512);        // P1 taps h0-8..h0+32
    const bool xin = (w0 >= 8) && (2 * w0 + 83 < W_F4);   // bx in [1,14]

    const float4* img  = in  + (size_t)blockIdx.z * IMG_F4;
    float4*       oimg = out + (size_t)blockIdx.z * IMG_F4;

    // ---- P1: vertical min, global -> sA. (c in [0,100)) x runs {16,16} ----
    // sA row s <-> eroded abs row h0-4+s; taps for s: input rows h0-8+s..h0+1+s.
    if (t < 2 * 128) {
        const int p  = t >> 7;               // wave-uniform run id (2 waves/run)
        const int id = t & 127;
        if (id < CA) {
            const int s0    = p * 16;
            const int hbase = h0 - 8 + s0;
            const int colf4 = w0 * 2 - 16 + id;
            float4 o[16];
            if (yin) {
                const bool colok = (colf4 >= 0) & (colf4 < W_F4);  // xin -> true
                if (colok) {
                    auto tap = [&](int q) { return img[(size_t)(hbase + q) * W_F4 + colf4]; };
                    gw_run<16, true>(tap, o);
#pragma unroll
                    for (int i = 0; i < 16; i++) sA[(s0 + i) * S_A + id] = o[i];
                } else {                     // whole column OOB -> +inf
#pragma unroll
                    for (int i = 0; i < 16; i++) sA[(s0 + i) * S_A + id] = pinf4;
                }
            } else {                         // rim: per-tap mask
                auto tap = [&](int q) {
                    int h = hbase + q;
                    bool ok = (colf4 >= 0) & (colf4 < W_F4) & (h >= 0) & (h < 512);
                    return ok ? img[(size_t)h * W_F4 + colf4] : pinf4;
                };
                gw_run<16, true>(tap, o);
#pragma unroll
                for (int i = 0; i < 16; i++) sA[(s0 + i) * S_A + id] = o[i];
            }
        }
    }
    __syncthreads();

    // ---- P2: horizontal min, sA -> sA in place. 192 tasks, 3 waves 100% fill ----
    // task t<192: c4 = t&1, row = (t>>1)&31, run u = t>>6 (wave-uniform).
    // out j in [j0, j0+R): eroded px w0-4+j; taps minV px j..j+9 (staged 50 px).
    // No masks: P1 staged +inf for OOB. Max tap col: u=2,q=21 -> 2*49+1 = 99.
    {
        const bool act = t < 192;
        const int u  = t >> 6;               // 0,1,2 wave-uniform
        int base = 0, j0 = 0;
        float4 o[14];
        if (act) {
            base = ((t >> 1) & 31) * S_A + (t & 1);
            j0 = u * 14;                     // 0,14,28
            auto tap = [&](int q) { return sA[base + 2 * (j0 + q)]; };
            if (u < 2) gw_run<14, true>(tap, o);
            else       gw_run<13, true>(tap, o);
        }
        __syncthreads();                     // all reads done before any write
        if (act) {
            if (u < 2) {
#pragma unroll
                for (int i = 0; i < 14; i++) sA[base + 2 * (j0 + i)] = o[i];
            } else {
#pragma unroll
                for (int i = 0; i < 13; i++) sA[base + 2 * (j0 + i)] = o[i];
            }
        }
    }
    __syncthreads();

    // ---- P3: vertical max, sA -> sA rows [0,23). (c in [0,82)) x runs {16,7} ----
    // out o: abs row h0+o; taps eroded rows s=o..o+9 (s<=31, exact). Tap = -inf
    // when eroded abs row h0-4+s outside [0,512) (dilation pads eroded -inf).
    {
        const int u  = t >> 7;               // wave-uniform (2 waves/run)
        const int id = t & 127;
        const bool act = (t < 2 * 128) && (id < 82);
        int c = 0, o0 = 0;
        float4 o[16];
        if (act) {
            c  = id;
            o0 = u * 16;                     // 0,16
            if (yin) {
                auto tap = [&](int q) { return sA[(o0 + q) * S_A + c]; };
                if (u == 0) gw_run<16, false>(tap, o);
                else        gw_run< 7, false>(tap, o);
            } else {
                auto tap = [&](int q) {
                    int s = o0 + q;
                    float4 val = sA[s * S_A + c];
                    int h = h0 - 4 + s;
                    return ((h >= 0) & (h < 512)) ? val : ninf4;
                };
                if (u == 0) gw_run<16, false>(tap, o);
                else        gw_run< 7, false>(tap, o);
            }
        }
        __syncthreads();                     // all reads done before any write
        if (act) {
            const int Rn = (u == 0) ? 16 : 7;
#pragma unroll
            for (int i = 0; i < 16; i++)
                if (i < Rn) sA[(o0 + i) * S_A + c] = o[i];
        }
    }
    __syncthreads();

    // ---- P4: horizontal max, sA -> sA cols [0,64). (c4 x 23 rows) x runs {16,16} ----
    // out x: px w0+x; taps eroded j=x..x+9 (j <= 40, exact). Tap = -inf when
    // eroded abs px w0-4+j outside [0,512).
    {
        const int u  = t >> 6;               // wave-uniform
        const int id = t & 63;
        const bool act = (t < 2 * 64) && (id < 2 * TH);
        int base = 0, x0 = 0;
        float4 o[16];
        if (act) {
            base = (id >> 1) * S_A + (id & 1);
            x0 = u * 16;                     // 0,16
            if (xin) {
                auto tap = [&](int q) { return sA[base + 2 * (x0 + q)]; };
                gw_run<16, false>(tap, o);
            } else {
                auto tap = [&](int q) {
                    int j = x0 + q;
                    float4 val = sA[base + 2 * j];
                    int px = w0 - 4 + j;
                    return ((px >= 0) & (px < 512)) ? val : ninf4;
                };
                gw_run<16, false>(tap, o);
            }
        }
        __syncthreads();                     // all reads done before any write
        if (act) {
#pragma unroll
            for (int i = 0; i < 16; i++)     // cols <= 63
                sA[base + 2 * (x0 + i)] = o[i];
        }
    }
    __syncthreads();

    // ---- P5: coalesced copy sA -> global (lanes = consecutive f4, 1 KB/wave) ----
    for (int idx = t; idx < TH * 64; idx += 512) {
        int r = idx >> 6;
        int c = idx & 63;
        int h = h0 + r;
        if (h < 512)
            oimg[(size_t)h * W_F4 + (size_t)(w0 * 2 + c)] = sA[r * S_A + c];
    }
}

extern "C" void kernel_launch(void* const* d_in, const int* in_sizes, int n_in,
                              void* d_out, int out_size, void* d_ws, size_t ws_size,
                              hipStream_t stream) {
    const float4* in  = (const float4*)d_in[0];
    float4*       out = (float4*)d_out;
    (void)d_ws; (void)ws_size;               // workspace not needed

    dim3 grid(512 / TW, (512 + TH - 1) / TH, 16);   // 16 x 23 x 16 = 5888 blocks
    opening<<<grid, 512, 0, stream>>>(in, out);
}